// Round 1
// baseline (416.001 us; speedup 1.0000x reference)
//
#include <hip/hip_runtime.h>
#include <hip/hip_bf16.h>

// AttentionWithContext: out[b,f] = sum_t a[b,t] x[b,t,f],
//   a = exp(ait)/ (sum_t exp(ait) + 1e-7),  ait = tanh(x@W + bias) . u
// Strategy: single fused pass over x. Each block = 64 timesteps of one b:
//   stage x-tile (fp32->bf16) in LDS, MFMA C[g][t] = Wt . x^T (Wt = bf16
//   pre-transposed W in ws, L2-resident), epilogue tanh+dot(u) -> ait ->
//   exp -> partial numerator (from LDS x) + partial denom via atomicAdd.
// x is read from HBM exactly ONCE (256 MiB -> ~42 us floor).

#define BB 128
#define TT 2048
#define FF 256
#define MM (BB * TT)          // 262144 rows
#define TQ 64                 // timesteps per block
#define NBLK (MM / TQ)        // 4096 blocks
#define LSTRIDE 264           // LDS row stride in bf16 elems (256 + 8 pad, keeps 16B align, 2-way banks)

using bf16x8 = __attribute__((ext_vector_type(8))) short;
using f32x4  = __attribute__((ext_vector_type(4))) float;
using u16x4  = __attribute__((ext_vector_type(4))) unsigned short;

__device__ __forceinline__ unsigned short f2bf(float f) {
  union { float f; unsigned u; } v; v.f = f;
  unsigned r = v.u + 0x7fffu + ((v.u >> 16) & 1u);   // RNE
  return (unsigned short)(r >> 16);
}
__device__ __forceinline__ float bf2f(unsigned short h) {
  union { unsigned u; float f; } v; v.u = ((unsigned)h) << 16;
  return v.f;
}
__device__ __forceinline__ float fast_tanh(float v) {
  float e = __expf(2.f * v);                 // inf-safe: e=inf -> result 1
  return 1.f - __fdividef(2.f, e + 1.f);     // e=0 -> -1
}

// ---------------- prep: Wt[g][k] = bf16(W[k][g]); zero num+denom ----------------
__global__ void prep(const float* __restrict__ W, unsigned short* __restrict__ Wt,
                     float* __restrict__ zr) {
  int i = blockIdx.x * 256 + threadIdx.x;
  if (i < FF * FF) {
    int f = i >> 8, g = i & 255;             // coalesced read of W[f][g]
    Wt[g * FF + f] = f2bf(W[i]);
  }
  int j = i - FF * FF;
  if (j >= 0 && j < BB * FF + BB) zr[j] = 0.f;
}

// ---------------- main fused kernel ----------------
__global__ __launch_bounds__(256)
void attn_main(const float* __restrict__ x, const unsigned short* __restrict__ Wt,
               const float* __restrict__ bias, const float* __restrict__ uvec,
               float* __restrict__ num, float* __restrict__ denom) {
  __shared__ unsigned short xb[TQ * LSTRIDE];   // 33792 B
  __shared__ float part[4][TQ];                 // per-wave g-partials of ait
  __shared__ float ebuf[TQ];                    // exp(ait)

  const int tid  = threadIdx.x;
  const int wave = tid >> 6;
  const int lane = tid & 63;
  const int q    = lane >> 4;       // quad
  const int ln   = lane & 15;
  const long m0  = (long)blockIdx.x * TQ;
  const int bidx = (int)(m0 >> 11); // m0 / T

  // ---- stage x tile -> LDS bf16 (coalesced: wave reads 1024B contiguous) ----
  {
    const float* src = x + m0 * FF;
    #pragma unroll
    for (int r2 = 0; r2 < (TQ * FF) / 1024; ++r2) {   // 16 rounds
      int e = r2 * 1024 + tid * 4;
      f32x4 v = *(const f32x4*)(src + e);
      int row = e >> 8, col = e & (FF - 1);
      u16x4 w = { f2bf(v.x), f2bf(v.y), f2bf(v.z), f2bf(v.w) };
      *(u16x4*)(&xb[row * LSTRIDE + col]) = w;
    }
  }
  __syncthreads();

  // ---- MFMA: C[g][t_local]; wave w owns g in [64w, 64w+64) ----
  f32x4 acc[4][TQ / 16];
  #pragma unroll
  for (int i = 0; i < 4; ++i)
    #pragma unroll
    for (int j = 0; j < TQ / 16; ++j)
      acc[i][j] = (f32x4){0.f, 0.f, 0.f, 0.f};

  const int gbase = wave * 64;
  #pragma unroll
  for (int kk = 0; kk < FF; kk += 32) {
    bf16x8 afr[4];
    #pragma unroll
    for (int gt = 0; gt < 4; ++gt) {
      int g = gbase + gt * 16 + ln;
      afr[gt] = *(const bf16x8*)(Wt + g * FF + kk + q * 8);   // A[m=ln][k=q*8+j], L2-hit
    }
    #pragma unroll
    for (int tt = 0; tt < TQ / 16; ++tt) {
      bf16x8 bfr = *(const bf16x8*)(&xb[(tt * 16 + ln) * LSTRIDE + kk + q * 8]); // B[k][n=ln]
      #pragma unroll
      for (int gt = 0; gt < 4; ++gt)
        acc[gt][tt] = __builtin_amdgcn_mfma_f32_16x16x32_bf16(afr[gt], bfr, acc[gt][tt], 0, 0, 0);
    }
  }

  // ---- epilogue: ait[t] = sum_g tanh(C[g][t]+bias[g]) * u[g] ----
  float bi[4][4], uu[4][4];
  #pragma unroll
  for (int gt = 0; gt < 4; ++gt)
    #pragma unroll
    for (int r = 0; r < 4; ++r) {
      int g = gbase + gt * 16 + q * 4 + r;    // C row = q*4 + reg
      bi[gt][r] = bias[g];
      uu[gt][r] = uvec[g];
    }
  #pragma unroll
  for (int tt = 0; tt < TQ / 16; ++tt) {
    float s = 0.f;
    #pragma unroll
    for (int gt = 0; gt < 4; ++gt)
      #pragma unroll
      for (int r = 0; r < 4; ++r)
        s += fast_tanh(acc[gt][tt][r] + bi[gt][r]) * uu[gt][r];
    s += __shfl_xor(s, 16, 64);               // reduce across quads
    s += __shfl_xor(s, 32, 64);
    if (lane < 16) part[wave][tt * 16 + lane] = s;
  }
  __syncthreads();

  // ---- combine 4 waves, exp, partial denom (wave 0 only) ----
  if (tid < TQ) {
    float ait = part[0][tid] + part[1][tid] + part[2][tid] + part[3][tid];
    float e = __expf(ait);
    ebuf[tid] = e;
    float s2 = e;
    #pragma unroll
    for (int off = 32; off > 0; off >>= 1) s2 += __shfl_xor(s2, off, 64);
    if (tid == 0) atomicAdd(&denom[bidx], s2);
  }
  __syncthreads();

  // ---- partial numerator from LDS: num[bidx][f] += sum_t e[t] * x[t][f] ----
  {
    int fp = (tid & 127) * 2;     // f pair
    int half = tid >> 7;          // split t-range across two thread groups
    float a0 = 0.f, a1 = 0.f;
    #pragma unroll
    for (int i = 0; i < TQ / 2; ++i) {
      int tl = half * (TQ / 2) + i;
      float e = ebuf[tl];
      unsigned xv = *(const unsigned*)(&xb[tl * LSTRIDE + fp]);
      a0 += e * bf2f((unsigned short)(xv & 0xffffu));
      a1 += e * bf2f((unsigned short)(xv >> 16));
    }
    atomicAdd(&num[bidx * FF + fp],     a0);
    atomicAdd(&num[bidx * FF + fp + 1], a1);
  }
}

// ---------------- finalize: out = num / (denom + eps) ----------------
__global__ void finalize(const float* __restrict__ num, const float* __restrict__ denom,
                         float* __restrict__ out) {
  int i = blockIdx.x * 256 + threadIdx.x;    // 32768
  out[i] = num[i] / (denom[i >> 8] + 1e-7f);
}

extern "C" void kernel_launch(void* const* d_in, const int* in_sizes, int n_in,
                              void* d_out, int out_size, void* d_ws, size_t ws_size,
                              hipStream_t stream) {
  const float* x  = (const float*)d_in[0];
  const float* W  = (const float*)d_in[1];
  const float* bv = (const float*)d_in[2];
  const float* uv = (const float*)d_in[3];
  float* out = (float*)d_out;

  unsigned short* Wt = (unsigned short*)d_ws;                 // 131072 B
  float* num   = (float*)((char*)d_ws + FF * FF * 2);         // 131072 B
  float* denom = num + BB * FF;                               // 512 B

  prep<<<(FF * FF + BB * FF + BB + 255) / 256, 256, 0, stream>>>(W, Wt, num);
  attn_main<<<NBLK, 256, 0, stream>>>(x, Wt, bv, uv, num, denom);
  finalize<<<(BB * FF) / 256, 256, 0, stream>>>(num, denom, out);
}

// Round 2
// 410.494 us; speedup vs baseline: 1.0134x; 1.0134x over previous
//
#include <hip/hip_runtime.h>
#include <hip/hip_bf16.h>

// AttentionWithContext: out[b,f] = sum_t a[b,t] x[b,t,f],
//   a = exp(ait)/(sum_t exp(ait) + 1e-7),  ait = tanh(x@W + bias) . u
// Fused single pass over x. Each block = 64 timesteps of one b:
//   stage x-tile (fp32->bf16) in LDS, MFMA C[g][t] = Wt . x^T (Wt bf16 in ws,
//   L2-resident), epilogue tanh+dot(u) -> ait -> exp -> partial numerator
//   (x re-read from LDS) + partial denom via atomicAdd. x read from HBM once.
// R2: batched staging loads (launch_bounds(256,4) frees VGPRs to 128),
//     v_cvt_pk_bf16_f32 via __float22bfloat162_rn, cheap bf16 unpack.

#define BB 128
#define TT 2048
#define FF 256
#define MM (BB * TT)          // 262144 rows
#define TQ 64                 // timesteps per block
#define NBLK (MM / TQ)        // 4096 blocks
#define LSTRIDE 264           // LDS row stride in bf16 elems (+8 pad: 16B-aligned, 2-way banks)

using bf16x8 = __attribute__((ext_vector_type(8))) short;
using f32x4  = __attribute__((ext_vector_type(4))) float;
using u32x2  = __attribute__((ext_vector_type(2))) unsigned;

__device__ __forceinline__ unsigned short f2bf(float f) {
  union { float f; unsigned u; } v; v.f = f;
  unsigned r = v.u + 0x7fffu + ((v.u >> 16) & 1u);   // RNE
  return (unsigned short)(r >> 16);
}
__device__ __forceinline__ unsigned pk2bf(float a, float b) {
  __hip_bfloat162 h = __float22bfloat162_rn(make_float2(a, b));  // v_cvt_pk_bf16_f32 on gfx950
  union { __hip_bfloat162 h; unsigned u; } v; v.h = h;
  return v.u;
}
__device__ __forceinline__ float fast_tanh(float v) {
  float e = __expf(2.f * v);                 // inf-safe: e=inf -> 1
  return 1.f - __fdividef(2.f, e + 1.f);     // e=0 -> -1
}

// ---------------- prep: Wt[g][k] = bf16(W[k][g]); zero num+denom ----------------
__global__ void prep(const float* __restrict__ W, unsigned short* __restrict__ Wt,
                     float* __restrict__ zr) {
  int i = blockIdx.x * 256 + threadIdx.x;
  if (i < FF * FF) {
    int f = i >> 8, g = i & 255;             // coalesced read of W[f][g]
    Wt[g * FF + f] = f2bf(W[i]);
  }
  int j = i - FF * FF;
  if (j >= 0 && j < BB * FF + BB) zr[j] = 0.f;
}

// ---------------- main fused kernel ----------------
__global__ __launch_bounds__(256, 4)   // LDS caps 4 blocks/CU anyway -> allow 128 VGPRs
void attn_main(const float* __restrict__ x, const unsigned short* __restrict__ Wt,
               const float* __restrict__ bias, const float* __restrict__ uvec,
               float* __restrict__ num, float* __restrict__ denom) {
  __shared__ unsigned short xb[TQ * LSTRIDE];   // 33792 B
  __shared__ float part[4][TQ];                 // per-wave g-partials of ait
  __shared__ float ebuf[TQ];                    // exp(ait)

  const int tid  = threadIdx.x;
  const int wave = tid >> 6;
  const int lane = tid & 63;
  const int q    = lane >> 4;       // quad
  const int ln   = lane & 15;
  const long m0  = (long)blockIdx.x * TQ;
  const int bidx = (int)(m0 >> 11); // m0 / T

  // ---- stage x tile -> LDS bf16. All 16 loads issued before any use ----
  {
    const float* src = x + m0 * FF + tid * 4;
    f32x4 v[16];
    #pragma unroll
    for (int r = 0; r < 16; ++r) v[r] = *(const f32x4*)(src + r * 1024);
    #pragma unroll
    for (int r = 0; r < 16; ++r) {
      int e = r * 1024 + tid * 4;
      int row = e >> 8, col = e & (FF - 1);
      u32x2 w = { pk2bf(v[r].x, v[r].y), pk2bf(v[r].z, v[r].w) };
      *(u32x2*)(&xb[row * LSTRIDE + col]) = w;
    }
  }
  __syncthreads();

  // ---- MFMA: C[g][t_local]; wave w owns g in [64w, 64w+64) ----
  f32x4 acc[4][TQ / 16];
  #pragma unroll
  for (int i = 0; i < 4; ++i)
    #pragma unroll
    for (int j = 0; j < TQ / 16; ++j)
      acc[i][j] = (f32x4){0.f, 0.f, 0.f, 0.f};

  const int gbase = wave * 64;
  #pragma unroll
  for (int kk = 0; kk < FF; kk += 32) {
    bf16x8 afr[4];
    #pragma unroll
    for (int gt = 0; gt < 4; ++gt) {
      int g = gbase + gt * 16 + ln;
      afr[gt] = *(const bf16x8*)(Wt + g * FF + kk + q * 8);   // A[m=ln][k=q*8+j], L2-hit
    }
    #pragma unroll
    for (int tt = 0; tt < TQ / 16; ++tt) {
      bf16x8 bfr = *(const bf16x8*)(&xb[(tt * 16 + ln) * LSTRIDE + kk + q * 8]); // B[k][n=ln]
      #pragma unroll
      for (int gt = 0; gt < 4; ++gt)
        acc[gt][tt] = __builtin_amdgcn_mfma_f32_16x16x32_bf16(afr[gt], bfr, acc[gt][tt], 0, 0, 0);
    }
  }

  // ---- epilogue: ait[t] = sum_g tanh(C[g][t]+bias[g]) * u[g] ----
  float bi[4][4], uu[4][4];
  #pragma unroll
  for (int gt = 0; gt < 4; ++gt)
    #pragma unroll
    for (int r = 0; r < 4; ++r) {
      int g = gbase + gt * 16 + q * 4 + r;    // C row = q*4 + reg
      bi[gt][r] = bias[g];
      uu[gt][r] = uvec[g];
    }
  #pragma unroll
  for (int tt = 0; tt < TQ / 16; ++tt) {
    float s = 0.f;
    #pragma unroll
    for (int gt = 0; gt < 4; ++gt)
      #pragma unroll
      for (int r = 0; r < 4; ++r)
        s += fast_tanh(acc[gt][tt][r] + bi[gt][r]) * uu[gt][r];
    s += __shfl_xor(s, 16, 64);               // reduce across quads
    s += __shfl_xor(s, 32, 64);
    if (lane < 16) part[wave][tt * 16 + lane] = s;
  }
  __syncthreads();

  // ---- combine 4 waves, exp, partial denom (wave 0 only) ----
  if (tid < TQ) {
    float ait = part[0][tid] + part[1][tid] + part[2][tid] + part[3][tid];
    float e = __expf(ait);
    ebuf[tid] = e;
    float s2 = e;
    #pragma unroll
    for (int off = 32; off > 0; off >>= 1) s2 += __shfl_xor(s2, off, 64);
    if (tid == 0) atomicAdd(&denom[bidx], s2);
  }
  __syncthreads();

  // ---- partial numerator from LDS: num[bidx][f] += sum_t e[t] * x[t][f] ----
  {
    int fp = (tid & 127) * 2;     // f pair
    int half = tid >> 7;          // split t-range across two thread groups
    float a0 = 0.f, a1 = 0.f;
    #pragma unroll
    for (int i = 0; i < TQ / 2; ++i) {
      int tl = half * (TQ / 2) + i;
      float e = ebuf[tl];
      unsigned xv = *(const unsigned*)(&xb[tl * LSTRIDE + fp]);
      union { unsigned u; float f; } lo, hi;
      lo.u = xv << 16;
      hi.u = xv & 0xffff0000u;
      a0 += e * lo.f;
      a1 += e * hi.f;
    }
    atomicAdd(&num[bidx * FF + fp],     a0);
    atomicAdd(&num[bidx * FF + fp + 1], a1);
  }
}

// ---------------- finalize: out = num / (denom + eps) ----------------
__global__ void finalize(const float* __restrict__ num, const float* __restrict__ denom,
                         float* __restrict__ out) {
  int i = blockIdx.x * 256 + threadIdx.x;    // 32768
  out[i] = num[i] / (denom[i >> 8] + 1e-7f);
}

extern "C" void kernel_launch(void* const* d_in, const int* in_sizes, int n_in,
                              void* d_out, int out_size, void* d_ws, size_t ws_size,
                              hipStream_t stream) {
  const float* x  = (const float*)d_in[0];
  const float* W  = (const float*)d_in[1];
  const float* bv = (const float*)d_in[2];
  const float* uv = (const float*)d_in[3];
  float* out = (float*)d_out;

  unsigned short* Wt = (unsigned short*)d_ws;                 // 131072 B
  float* num   = (float*)((char*)d_ws + FF * FF * 2);         // 131072 B
  float* denom = num + BB * FF;                               // 512 B

  prep<<<(FF * FF + BB * FF + BB + 255) / 256, 256, 0, stream>>>(W, Wt, num);
  attn_main<<<NBLK, 256, 0, stream>>>(x, Wt, bv, uv, num, denom);
  finalize<<<(BB * FF) / 256, 256, 0, stream>>>(num, denom, out);
}